// Round 9
// baseline (123.294 us; speedup 1.0000x reference)
//
#include <hip/hip_runtime.h>

typedef _Float16 half8 __attribute__((ext_vector_type(8)));
typedef float floatx16 __attribute__((ext_vector_type(16)));

#define TPB    256           // 4 waves
#define RPTS   256           // db points staged per round (= TPB: 1 pt/thread)
#define NTILE  (RPTS / 32)   // 8 tiles of 32 db points
#define SMH    (RPTS * 16)   // 4096 halfs = 8 KiB per buffer
#define NSPLIT 4             // md-split: blocks per (qblock, dir) pair

// 32x32x16 f16 MFMA, SWAPPED-OPERAND form (R6): db points are the A operand
// (rows), queries are the B operand (cols). D col = lane&31 = query, so the
// min-over-db axis lies in the 16 accumulator REGS -> in-lane min tree,
// merged across h-halves with one shfl_xor(32) at the end.
// R8 fold: HYBRID. Level 1 = plain fminf on the 16 MFMA results (8 v_min_f32;
// compiler inserts the required MFMA->VALU hazard wait states). Levels 2+ =
// inline-asm v_min3_f32 on those VALU results only (4 ops).
// R7 lesson (FAILED absmax=144): inline asm must NEVER directly read MFMA
// results — LLVM's hazard recognizer checks inline-asm DEFs but not READS of
// an in-flight MFMA destination, so the asm sampled stale accumulators.
// Block = 256 queries x ONE md-chunk (md/NSPLIT db points); partial per-query
// mins -> ws[chunk][dir][b][q]; chamfer_reduce mins over chunks + mean.
// md-split rationale (R4/R5): without it only 16 waves/CU exist chip-wide.
// R4 lesson: no __launch_bounds__(256,8) — reg budget split arch/accum,
//   spills, scratch-bandwidth kernel. Residency follows ACTUAL usage.
// R3 lesson: keep the sweep rolled (#pragma unroll 1), fold each MFMA result
//   immediately — never hold 4 floatx16 live.
// R1 lesson: staging data in named scalars only — never arrays/pointers.
// K-slots (11 of 16): A(db): (xh,xl,xh,yh,yl,yh,zh,zl | zh,hqh,hql,0..)
//                     B(qry): (-xh,-xh,-xl,-yh,-yh,-yl,-zh,-zh | -zl,1,1,0..)
// => acc = 0.5||q_db||^2 - p.q_db (split-f16); dist = 2*(0.5||p||^2 + min acc).
// A: row = lane&31, k = (lane>>5)*8+j.  B: col = lane&31, same k.
// C/D: col = lane&31 (query), row(db) = (reg&3)+8*(reg>>2)+4*(lane>>5)
//   -> regs cover 16 of 32 db rows; h-partner lane covers the other 16.

__device__ __forceinline__ float vmin3(float a, float b, float c) {
    float r;
    asm("v_min3_f32 %0, %1, %2, %3" : "=v"(r) : "v"(a), "v"(b), "v"(c));
    return r;
}

// min(rmq, d[0..15]): level 1 via fminf (hazard-safe on MFMA results),
// upper levels via asm v_min3 (inputs are VALU results — no MFMA hazard).
__device__ __forceinline__ float fold16_hybrid(floatx16 d, float rmq) {
    float m0 = fminf(d[0],  d[1]);
    float m1 = fminf(d[2],  d[3]);
    float m2 = fminf(d[4],  d[5]);
    float m3 = fminf(d[6],  d[7]);
    float m4 = fminf(d[8],  d[9]);
    float m5 = fminf(d[10], d[11]);
    float m6 = fminf(d[12], d[13]);
    float m7 = fminf(d[14], d[15]);
    float t0 = vmin3(m0, m1, m2);
    float t1 = vmin3(m3, m4, m5);
    float t2 = vmin3(m6, m7, t0);
    return vmin3(rmq, t1, t2);
}

__device__ __forceinline__ void wr_point(_Float16* __restrict__ smb, int j,
                                         float x, float y, float z) {
    float hq = 0.5f * (x * x + y * y + z * z);
    _Float16 xh = (_Float16)x, yh = (_Float16)y, zh = (_Float16)z;
    _Float16 xl = (_Float16)(x - (float)xh);
    _Float16 yl = (_Float16)(y - (float)yh);
    _Float16 zl = (_Float16)(z - (float)zh);
    _Float16 qh = (_Float16)hq;
    _Float16 ql = (_Float16)(hq - (float)qh);
    const _Float16 hz = (_Float16)0.0f;
    int t = j >> 5, c = j & 31;
    half8 v0, v1;
    v0[0] = xh; v0[1] = xl; v0[2] = xh; v0[3] = yh;
    v0[4] = yl; v0[5] = yh; v0[6] = zh; v0[7] = zl;
    v1[0] = zh; v1[1] = qh; v1[2] = ql; v1[3] = hz;
    v1[4] = hz; v1[5] = hz; v1[6] = hz; v1[7] = hz;
    *(half8*)&smb[t * 512 + c * 8]       = v0;   // k-half 0
    *(half8*)&smb[t * 512 + 256 + c * 8] = v1;   // k-half 1
}

__global__ __launch_bounds__(TPB, 4) void chamfer_mfma(const float* __restrict__ xyz1,
                                                       const float* __restrict__ xyz2,
                                                       float* __restrict__ ws,
                                                       int N, int M, int QCAP) {
    const int b = blockIdx.y, dir = blockIdx.z;
    const int B = gridDim.y;
    const int qblock = (int)blockIdx.x / NSPLIT;
    const int chunk  = (int)blockIdx.x % NSPLIT;
    const float* __restrict__ P = dir ? xyz2 + (size_t)b * M * 3 : xyz1 + (size_t)b * N * 3;
    const float* __restrict__ Q = dir ? xyz1 + (size_t)b * N * 3 : xyz2 + (size_t)b * M * 3;
    const int nq = dir ? M : N;
    const int md = dir ? N : M;

    if (qblock * 256 >= nq) return;   // block-uniform, before any barrier

    // chunk range: CH rounds up so NSPLIT*CH covers md; clamp-pad handles excess
    const int CH   = ((md + NSPLIT * RPTS - 1) / (NSPLIT * RPTS)) * RPTS;
    const int base = chunk * CH;
    const int nrounds = CH / RPTS;    // >= 1

    __shared__ __align__(16) _Float16 smB[2][SMH];

    const int tid = (int)threadIdx.x;
    const int w   = tid >> 6;
    const int l   = tid & 63;
    const int m   = l & 31;      // B col (query) this lane serves
    const int h   = l >> 5;      // k-half: k = h*8 + j

    const _Float16 hz = (_Float16)0.0f, hone = (_Float16)1.0f;
    const int qb = qblock * 256 + w * 64;

    // ---- Build the wave's 2 query B-fragments (held for the whole kernel) ----
    half8 qfr[2];
#pragma unroll
    for (int g = 0; g < 2; ++g) {
        int idx = qb + g * 32 + m;
        int ci  = idx < nq ? idx : nq - 1;
        float x = P[3 * ci], y = P[3 * ci + 1], z = P[3 * ci + 2];
        _Float16 xh = (_Float16)x, yh = (_Float16)y, zh = (_Float16)z;
        _Float16 xl = (_Float16)(x - (float)xh);
        _Float16 yl = (_Float16)(y - (float)yh);
        _Float16 zl = (_Float16)(z - (float)zh);
        half8 a;
        if (h == 0) {
            a[0] = -xh; a[1] = -xh; a[2] = -xl; a[3] = -yh;
            a[4] = -yh; a[5] = -yl; a[6] = -zh; a[7] = -zh;
        } else {
            a[0] = -zl; a[1] = hone; a[2] = hone; a[3] = hz;
            a[4] = hz;  a[5] = hz;   a[6] = hz;  a[7] = hz;
        }
        qfr[g] = a;
    }

    // ---- staging registers: named scalars ONLY (R1 lesson) ----
    float sx0, sy0, sz0;
#define LDPTS(rr) {                                                   \
        int g0 = base + (rr) * RPTS + tid;                            \
        g0 = g0 < md ? g0 : md - 1;  /* clamp-pad: dups never change a min */ \
        sx0 = Q[3 * g0]; sy0 = Q[3 * g0 + 1]; sz0 = Q[3 * g0 + 2];    \
    }
#define WRPTS(bb) { wr_point(&smB[bb][0], tid, sx0, sy0, sz0); }

    float rmq0 = 3.0e38f, rmq1 = 3.0e38f;   // running min for query cols g=0,1

    const floatx16 czero = {0.0f, 0.0f, 0.0f, 0.0f, 0.0f, 0.0f, 0.0f, 0.0f,
                            0.0f, 0.0f, 0.0f, 0.0f, 0.0f, 0.0f, 0.0f, 0.0f};

    // ---- prologue: buf0 <- round 0; regs <- round 1 ----
    LDPTS(0);
    WRPTS(0);
    if (nrounds > 1) LDPTS(1);
    __syncthreads();

    const _Float16* bp0 = &smB[0][h * 256 + m * 8];
    const _Float16* bp1 = &smB[1][h * 256 + m * 8];

    int cur = 0;
    for (int r = 0; r < nrounds; ++r) {
        // write regs(r+1) -> other buffer; then issue loads for r+2
        if (r + 1 < nrounds) {
            WRPTS(cur ^ 1);
            if (r + 2 < nrounds) LDPTS(r + 2);
        }

        // ---- Sweep buf[cur]: rolled, fold each MFMA result immediately ----
        const _Float16* bp = cur ? bp1 : bp0;
#pragma unroll 1
        for (int t = 0; t < NTILE; t += 2) {
            half8 a0 = *(const half8*)(bp + t * 512);
            half8 a1 = *(const half8*)(bp + t * 512 + 512);
            floatx16 d;
            d = __builtin_amdgcn_mfma_f32_32x32x16_f16(a0, qfr[0], czero, 0, 0, 0);
            rmq0 = fold16_hybrid(d, rmq0);
            d = __builtin_amdgcn_mfma_f32_32x32x16_f16(a0, qfr[1], czero, 0, 0, 0);
            rmq1 = fold16_hybrid(d, rmq1);
            d = __builtin_amdgcn_mfma_f32_32x32x16_f16(a1, qfr[0], czero, 0, 0, 0);
            rmq0 = fold16_hybrid(d, rmq0);
            d = __builtin_amdgcn_mfma_f32_32x32x16_f16(a1, qfr[1], czero, 0, 0, 0);
            rmq1 = fold16_hybrid(d, rmq1);
        }

        if (r + 1 < nrounds) __syncthreads();   // uniform; last round skips
        cur ^= 1;
    }

    // ---- Merge h-halves (regs covered 16 of 32 db rows; partner has rest) ----
    rmq0 = fminf(rmq0, __shfl_xor(rmq0, 32, 64));
    rmq1 = fminf(rmq1, __shfl_xor(rmq1, 32, 64));

    // ---- Emit: lane l owns query qb+l (h*32+m == l); coalesced write ----
    float* __restrict__ wsd = ws + (((size_t)chunk * 2 + dir) * B + b) * QCAP;
    const int idx = qb + l;
    const float val = h ? rmq1 : rmq0;
    if (idx < nq) wsd[idx] = val;
}

// Min over chunks + mean over queries. Blocks: (b, dir, qsplit of 4).
// (R6 proven form — no inline asm here; this kernel is ~3 us, not critical.)
__global__ __launch_bounds__(256) void chamfer_reduce(const float* __restrict__ xyz1,
                                                      const float* __restrict__ xyz2,
                                                      const float* __restrict__ ws,
                                                      float* __restrict__ out,
                                                      int N, int M, int QCAP) {
    const int b = (int)blockIdx.x, dir = (int)blockIdx.y;
    const int B = gridDim.x;
    const float* __restrict__ P = dir ? xyz2 + (size_t)b * M * 3 : xyz1 + (size_t)b * N * 3;
    const int nq = dir ? M : N;
    const size_t cs = (size_t)2 * B * QCAP;                       // chunk stride
    const float* __restrict__ w0 = ws + ((size_t)dir * B + b) * QCAP;

    float s = 0.0f;
    for (int q = (int)threadIdx.x + (int)blockIdx.z * 256; q < nq; q += 256 * (int)gridDim.z) {
        float v = w0[q];
#pragma unroll
        for (int c = 1; c < NSPLIT; ++c) v = fminf(v, w0[c * cs + q]);
        float x = P[3 * q], y = P[3 * q + 1], z = P[3 * q + 2];
        s += v + 0.5f * (x * x + y * y + z * z);
    }
#pragma unroll
    for (int off = 32; off > 0; off >>= 1) s += __shfl_down(s, off, 64);
    __shared__ float red[4];
    if ((threadIdx.x & 63) == 0) red[threadIdx.x >> 6] = s;
    __syncthreads();
    if (threadIdx.x == 0) {
        float t = (red[0] + red[1]) + (red[2] + red[3]);
        atomicAdd(out + b, t * (2.0f / (float)nq));   // dist = 2*(ph + min acc)
    }
}

extern "C" void kernel_launch(void* const* d_in, const int* in_sizes, int n_in,
                              void* d_out, int out_size, void* d_ws, size_t ws_size,
                              hipStream_t stream) {
    const float* xyz1 = (const float*)d_in[0];
    const float* xyz2 = (const float*)d_in[1];
    float* out = (float*)d_out;

    const int B = out_size;
    const int N = in_sizes[0] / (3 * B);
    const int M = in_sizes[1] / (3 * B);

    hipMemsetAsync(d_out, 0, (size_t)B * sizeof(float), stream);

    const int qmax    = N > M ? N : M;
    const int qblocks = (qmax + 255) / 256;
    const int QCAP    = qblocks * 256;
    // ws usage: NSPLIT * 2 * B * QCAP * 4 bytes (= 4 MiB at B=32, QCAP=4096)

    dim3 grid(qblocks * NSPLIT, B, 2);
    chamfer_mfma<<<grid, dim3(TPB), 0, stream>>>(xyz1, xyz2, (float*)d_ws, N, M, QCAP);
    chamfer_reduce<<<dim3(B, 2, 4), dim3(256), 0, stream>>>(xyz1, xyz2, (float*)d_ws, out, N, M, QCAP);
}

// Round 10
// 101.145 us; speedup vs baseline: 1.2190x; 1.2190x over previous
//
#include <hip/hip_runtime.h>

typedef _Float16 half8 __attribute__((ext_vector_type(8)));
typedef float floatx16 __attribute__((ext_vector_type(16)));

#define TPB    256            // 4 waves
#define CHUNK  1024           // db points per block (single-shot staged)
#define NTILE  (CHUNK / 32)   // 32 tiles of 32 db points
#define SMH    (CHUNK * 16)   // 16384 halfs = 32 KiB

// 32x32x16 f16 MFMA, SWAPPED-OPERAND form (R6): db points are the A operand
// (rows), queries are the B operand (cols). D col = lane&31 = query, so the
// min-over-db axis lies in the 16 accumulator REGS -> in-lane fminf tree,
// merged across h-halves with one shfl_xor(32) at the end.
// R10: SINGLE-SHOT staging. The block's whole 1024-pt chunk (32 KiB formatted)
// is staged in the prologue, ONE barrier, then an uninterrupted 32-tile sweep
// with 1-ahead LDS prefetch (branchless wrap) — removes 3 barriers and all
// per-round double-buffer bookkeeping. R6's idle fraction (~40% of cycles,
// VALU+MFMA ~61% combined) was barrier/pipeline overhead, not op count.
// R7 lesson (FAILED absmax=144): inline asm must never READ MFMA results —
//   LLVM hazard recognizer doesn't cover asm reads of in-flight MFMA dests.
// R9 lesson (REGRESSED 76us, 67 VALU-ops/MFMA): inline-asm v_min3 in the fold
//   forces "v"-class constraints -> allocator copy-storm (VGPR 24). NO inline
//   asm in the fold path; plain fminf (R6) is the fastest verified form.
// R4 lesson: no __launch_bounds__(256,8) — reg budget collapse -> rm spill.
// R3 lesson: sweep stays rolled (#pragma unroll 1); fold each MFMA result
//   immediately — never hold 4 floatx16 live.
// R1 lesson: staging data in named scalars only — never arrays/pointers.
// Block = 256 queries x ONE md-chunk (1024 db points); partial per-query mins
// -> ws[chunk][dir][b][q]; chamfer_reduce mins over chunks + mean.
// K-slots (11 of 16): A(db): (xh,xl,xh,yh,yl,yh,zh,zl | zh,hqh,hql,0..)
//                     B(qry): (-xh,-xh,-xl,-yh,-yh,-yl,-zh,-zh | -zl,1,1,0..)
// => acc = 0.5||q_db||^2 - p.q_db (split-f16); dist = 2*(0.5||p||^2 + min acc).
// A: row = lane&31, k = (lane>>5)*8+j.  B: col = lane&31, same k.
// C/D: col = lane&31 (query), row(db) = (reg&3)+8*(reg>>2)+4*(lane>>5)
//   -> regs cover 16 of 32 db rows; h-partner lane covers the other 16.

// min of 16 accumulator regs (R6 proven form — plain fminf, min3-friendly shape)
__device__ __forceinline__ float fold16(floatx16 d) {
    float m0 = fminf(fminf(d[0],  d[1]),  d[2]);
    float m1 = fminf(fminf(d[3],  d[4]),  d[5]);
    float m2 = fminf(fminf(d[6],  d[7]),  d[8]);
    float m3 = fminf(fminf(d[9],  d[10]), d[11]);
    float m4 = fminf(fminf(d[12], d[13]), d[14]);
    float n0 = fminf(fminf(m0, m1), m2);
    float n1 = fminf(fminf(m3, m4), d[15]);
    return fminf(n0, n1);
}

__device__ __forceinline__ void wr_point(_Float16* __restrict__ smb, int j,
                                         float x, float y, float z) {
    float hq = 0.5f * (x * x + y * y + z * z);
    _Float16 xh = (_Float16)x, yh = (_Float16)y, zh = (_Float16)z;
    _Float16 xl = (_Float16)(x - (float)xh);
    _Float16 yl = (_Float16)(y - (float)yh);
    _Float16 zl = (_Float16)(z - (float)zh);
    _Float16 qh = (_Float16)hq;
    _Float16 ql = (_Float16)(hq - (float)qh);
    const _Float16 hz = (_Float16)0.0f;
    int t = j >> 5, c = j & 31;
    half8 v0, v1;
    v0[0] = xh; v0[1] = xl; v0[2] = xh; v0[3] = yh;
    v0[4] = yl; v0[5] = yh; v0[6] = zh; v0[7] = zl;
    v1[0] = zh; v1[1] = qh; v1[2] = ql; v1[3] = hz;
    v1[4] = hz; v1[5] = hz; v1[6] = hz; v1[7] = hz;
    *(half8*)&smb[t * 512 + c * 8]       = v0;   // k-half 0
    *(half8*)&smb[t * 512 + 256 + c * 8] = v1;   // k-half 1
}

__global__ __launch_bounds__(TPB, 4) void chamfer_mfma(const float* __restrict__ xyz1,
                                                       const float* __restrict__ xyz2,
                                                       float* __restrict__ ws,
                                                       int N, int M, int QCAP,
                                                       int nchunks) {
    const int b = blockIdx.y, dir = blockIdx.z;
    const int B = gridDim.y;
    const int qblock = (int)blockIdx.x / nchunks;
    const int chunk  = (int)blockIdx.x % nchunks;
    const float* __restrict__ P = dir ? xyz2 + (size_t)b * M * 3 : xyz1 + (size_t)b * N * 3;
    const float* __restrict__ Q = dir ? xyz1 + (size_t)b * N * 3 : xyz2 + (size_t)b * M * 3;
    const int nq = dir ? M : N;
    const int md = dir ? N : M;

    if (qblock * 256 >= nq) return;   // block-uniform, before any barrier

    const int base = chunk * CHUNK;   // clamp-pad covers base+CHUNK > md

    __shared__ __align__(16) _Float16 smB[SMH];

    const int tid = (int)threadIdx.x;
    const int w   = tid >> 6;
    const int l   = tid & 63;
    const int m   = l & 31;      // B col (query) this lane serves
    const int h   = l >> 5;      // k-half: k = h*8 + j

    const _Float16 hz = (_Float16)0.0f, hone = (_Float16)1.0f;
    const int qb = qblock * 256 + w * 64;

    // ---- Build the wave's 2 query B-fragments (held for the whole kernel) ----
    half8 qfr[2];
#pragma unroll
    for (int g = 0; g < 2; ++g) {
        int idx = qb + g * 32 + m;
        int ci  = idx < nq ? idx : nq - 1;
        float x = P[3 * ci], y = P[3 * ci + 1], z = P[3 * ci + 2];
        _Float16 xh = (_Float16)x, yh = (_Float16)y, zh = (_Float16)z;
        _Float16 xl = (_Float16)(x - (float)xh);
        _Float16 yl = (_Float16)(y - (float)yh);
        _Float16 zl = (_Float16)(z - (float)zh);
        half8 a;
        if (h == 0) {
            a[0] = -xh; a[1] = -xh; a[2] = -xl; a[3] = -yh;
            a[4] = -yh; a[5] = -yl; a[6] = -zh; a[7] = -zh;
        } else {
            a[0] = -zl; a[1] = hone; a[2] = hone; a[3] = hz;
            a[4] = hz;  a[5] = hz;   a[6] = hz;  a[7] = hz;
        }
        qfr[g] = a;
    }

    // ---- Stage the whole 1024-pt chunk once (4 pts/thread, named scalars) ----
    {
        int g0 = base + tid;
        int g1 = base + tid + 256;
        int g2 = base + tid + 512;
        int g3 = base + tid + 768;
        g0 = g0 < md ? g0 : md - 1;   // clamp-pad: dups never change a min
        g1 = g1 < md ? g1 : md - 1;
        g2 = g2 < md ? g2 : md - 1;
        g3 = g3 < md ? g3 : md - 1;
        float x0 = Q[3 * g0], y0 = Q[3 * g0 + 1], z0 = Q[3 * g0 + 2];
        float x1 = Q[3 * g1], y1 = Q[3 * g1 + 1], z1 = Q[3 * g1 + 2];
        float x2 = Q[3 * g2], y2 = Q[3 * g2 + 1], z2 = Q[3 * g2 + 2];
        float x3 = Q[3 * g3], y3 = Q[3 * g3 + 1], z3 = Q[3 * g3 + 2];
        wr_point(smB, tid,       x0, y0, z0);
        wr_point(smB, tid + 256, x1, y1, z1);
        wr_point(smB, tid + 512, x2, y2, z2);
        wr_point(smB, tid + 768, x3, y3, z3);
    }
    __syncthreads();    // the kernel's ONLY barrier

    float rmq0 = 3.0e38f, rmq1 = 3.0e38f;   // running min for query cols g=0,1

    const floatx16 czero = {0.0f, 0.0f, 0.0f, 0.0f, 0.0f, 0.0f, 0.0f, 0.0f,
                            0.0f, 0.0f, 0.0f, 0.0f, 0.0f, 0.0f, 0.0f, 0.0f};

    // ---- Sweep 32 tiles, rolled, 1-ahead LDS prefetch (branchless wrap) ----
    const _Float16* bp = &smB[h * 256 + m * 8];
    half8 c0 = *(const half8*)(bp);
    half8 c1 = *(const half8*)(bp + 512);
#pragma unroll 1
    for (int t = 0; t < NTILE; t += 2) {
        const int t2 = (t + 2) & (NTILE - 1);        // wraps to 0 on last iter
        half8 n0 = *(const half8*)(bp + t2 * 512);
        half8 n1 = *(const half8*)(bp + t2 * 512 + 512);
        floatx16 d;
        d = __builtin_amdgcn_mfma_f32_32x32x16_f16(c0, qfr[0], czero, 0, 0, 0);
        rmq0 = fminf(rmq0, fold16(d));
        d = __builtin_amdgcn_mfma_f32_32x32x16_f16(c0, qfr[1], czero, 0, 0, 0);
        rmq1 = fminf(rmq1, fold16(d));
        d = __builtin_amdgcn_mfma_f32_32x32x16_f16(c1, qfr[0], czero, 0, 0, 0);
        rmq0 = fminf(rmq0, fold16(d));
        d = __builtin_amdgcn_mfma_f32_32x32x16_f16(c1, qfr[1], czero, 0, 0, 0);
        rmq1 = fminf(rmq1, fold16(d));
        c0 = n0; c1 = n1;
    }

    // ---- Merge h-halves (regs covered 16 of 32 db rows; partner has rest) ----
    rmq0 = fminf(rmq0, __shfl_xor(rmq0, 32, 64));
    rmq1 = fminf(rmq1, __shfl_xor(rmq1, 32, 64));

    // ---- Emit: lane l owns query qb+l (h*32+m == l); coalesced write ----
    float* __restrict__ wsd = ws + (((size_t)chunk * 2 + dir) * B + b) * QCAP;
    const int idx = qb + l;
    const float val = h ? rmq1 : rmq0;
    if (idx < nq) wsd[idx] = val;
}

// Min over chunks + mean over queries. Blocks: (b, dir, qsplit of 4).
__global__ __launch_bounds__(256) void chamfer_reduce(const float* __restrict__ xyz1,
                                                      const float* __restrict__ xyz2,
                                                      const float* __restrict__ ws,
                                                      float* __restrict__ out,
                                                      int N, int M, int QCAP,
                                                      int nchunks) {
    const int b = (int)blockIdx.x, dir = (int)blockIdx.y;
    const int B = gridDim.x;
    const float* __restrict__ P = dir ? xyz2 + (size_t)b * M * 3 : xyz1 + (size_t)b * N * 3;
    const int nq = dir ? M : N;
    const size_t cs = (size_t)2 * B * QCAP;                       // chunk stride
    const float* __restrict__ w0 = ws + ((size_t)dir * B + b) * QCAP;

    float s = 0.0f;
    for (int q = (int)threadIdx.x + (int)blockIdx.z * 256; q < nq; q += 256 * (int)gridDim.z) {
        float v = w0[q];
        for (int c = 1; c < nchunks; ++c) v = fminf(v, w0[c * cs + q]);
        float x = P[3 * q], y = P[3 * q + 1], z = P[3 * q + 2];
        s += v + 0.5f * (x * x + y * y + z * z);
    }
#pragma unroll
    for (int off = 32; off > 0; off >>= 1) s += __shfl_down(s, off, 64);
    __shared__ float red[4];
    if ((threadIdx.x & 63) == 0) red[threadIdx.x >> 6] = s;
    __syncthreads();
    if (threadIdx.x == 0) {
        float t = (red[0] + red[1]) + (red[2] + red[3]);
        atomicAdd(out + b, t * (2.0f / (float)nq));   // dist = 2*(ph + min acc)
    }
}

extern "C" void kernel_launch(void* const* d_in, const int* in_sizes, int n_in,
                              void* d_out, int out_size, void* d_ws, size_t ws_size,
                              hipStream_t stream) {
    const float* xyz1 = (const float*)d_in[0];
    const float* xyz2 = (const float*)d_in[1];
    float* out = (float*)d_out;

    const int B = out_size;
    const int N = in_sizes[0] / (3 * B);
    const int M = in_sizes[1] / (3 * B);

    hipMemsetAsync(d_out, 0, (size_t)B * sizeof(float), stream);

    const int qmax    = N > M ? N : M;
    const int qblocks = (qmax + 255) / 256;
    const int QCAP    = qblocks * 256;
    const int mdmax   = qmax;                    // chunks computed off max side
    const int nchunks = (mdmax + CHUNK - 1) / CHUNK;
    // ws usage: nchunks * 2 * B * QCAP * 4 bytes (= 4 MiB at B=32, QCAP=4096)

    dim3 grid(qblocks * nchunks, B, 2);
    chamfer_mfma<<<grid, dim3(TPB), 0, stream>>>(xyz1, xyz2, (float*)d_ws, N, M, QCAP, nchunks);
    chamfer_reduce<<<dim3(B, 2, 4), dim3(256), 0, stream>>>(xyz1, xyz2, (float*)d_ws, out, N, M, QCAP, nchunks);
}